// Round 1
// baseline (464.260 us; speedup 1.0000x reference)
//
#include <hip/hip_runtime.h>
#include <hip/hip_bf16.h>

// EfficientAttention: B=8 N=4096 C=768 H=12 D=64, M = B*N = 32768
// Stages: cast -> 3x GEMM(QKV, fp16 out) -> KV/Z partial reduce -> q-softmax @ kv (MFMA) -> GEMM(out, fp32)
// Workspace requirement: ~258 MB.

#define AS1 __attribute__((address_space(1)))
#define AS3 __attribute__((address_space(3)))

typedef __attribute__((ext_vector_type(8))) short    s16x8;
typedef __attribute__((ext_vector_type(4))) float    f32x4;
typedef __attribute__((ext_vector_type(4))) _Float16 f16x4;
typedef __attribute__((ext_vector_type(4))) unsigned short u16x4;

__device__ __forceinline__ unsigned short f2bf(float f) {
  union { float f; unsigned u; } v; v.f = f;
  unsigned r = v.u + 0x7FFFu + ((v.u >> 16) & 1u);   // round-to-nearest-even
  return (unsigned short)(r >> 16);
}

// ---------------- cast fp32 -> bf16 (vectorized 8/thread, G13) ----------------
__global__ __launch_bounds__(256) void cast_f32_bf16(const float* __restrict__ src,
                                                     unsigned short* __restrict__ dst, int n8) {
  int stride = gridDim.x * blockDim.x;
  for (int i = blockIdx.x * blockDim.x + threadIdx.x; i < n8; i += stride) {
    const f32x4* s = (const f32x4*)(src + (size_t)i * 8);
    f32x4 a = s[0], b = s[1];
    u16x4 lo, hi;
    lo[0] = f2bf(a[0]); lo[1] = f2bf(a[1]); lo[2] = f2bf(a[2]); lo[3] = f2bf(a[3]);
    hi[0] = f2bf(b[0]); hi[1] = f2bf(b[1]); hi[2] = f2bf(b[2]); hi[3] = f2bf(b[3]);
    u16x4* d = (u16x4*)(dst + (size_t)i * 8);
    d[0] = lo; d[1] = hi;
  }
}

// ---------------- GEMM: C[M,N] = A[M,K] * B[N,K]^T + bias (m97 structure) ----------------
// 128x128 tile, BK=64, 4 waves (2x2), 4x4 16x16x32 bf16 MFMA frags per wave,
// global_load_lds width=16 staging, 2 barriers per K-step.
template <typename OutT>
__global__ __launch_bounds__(256) void gemm_bt(const unsigned short* __restrict__ A,
                                               const unsigned short* __restrict__ Bm,
                                               const float* __restrict__ bias,
                                               OutT* __restrict__ C,
                                               int N, int K) {
  __shared__ unsigned short As[128 * 64];
  __shared__ unsigned short Bs[128 * 64];
  const int tid = threadIdx.x, lane = tid & 63, wid = tid >> 6;
  const int wm = wid >> 1, wn = wid & 1;
  const int m0 = blockIdx.y * 128, n0 = blockIdx.x * 128;
  f32x4 acc[4][4] = {};
  const int srow = lane >> 3;            // 0..7 within 8-row chunk
  const int scol = (lane & 7) * 8;       // 8 bf16 = 16B per lane

  for (int k0 = 0; k0 < K; k0 += 64) {
#pragma unroll
    for (int c = 0; c < 4; ++c) {
      int chunk = c * 4 + wid;                 // 16 chunks of 1KB per 16KB tile
      int row = chunk * 8 + srow;
      __builtin_amdgcn_global_load_lds(
          (const AS1 void*)(A + (size_t)(m0 + row) * K + k0 + scol),
          (AS3 void*)(As + chunk * 512), 16, 0, 0);
      __builtin_amdgcn_global_load_lds(
          (const AS1 void*)(Bm + (size_t)(n0 + row) * K + k0 + scol),
          (AS3 void*)(Bs + chunk * 512), 16, 0, 0);
    }
    __syncthreads();   // compiler emits vmcnt(0) drain before barrier
#pragma unroll
    for (int kk = 0; kk < 64; kk += 32) {
      s16x8 af[4], bf[4];
#pragma unroll
      for (int i = 0; i < 4; ++i)
        af[i] = *(const s16x8*)(As + (wm * 64 + i * 16 + (lane & 15)) * 64 + kk + (lane >> 4) * 8);
#pragma unroll
      for (int j = 0; j < 4; ++j)
        bf[j] = *(const s16x8*)(Bs + (wn * 64 + j * 16 + (lane & 15)) * 64 + kk + (lane >> 4) * 8);
#pragma unroll
      for (int i = 0; i < 4; ++i)
#pragma unroll
        for (int j = 0; j < 4; ++j)
          acc[i][j] = __builtin_amdgcn_mfma_f32_16x16x32_bf16(af[i], bf[j], acc[i][j], 0, 0, 0);
    }
    __syncthreads();
  }
  // epilogue: C/D layout col=lane&15, row=(lane>>4)*4+reg  [m89/m91-verified]
  const int col16 = lane & 15, row4 = (lane >> 4) * 4;
#pragma unroll
  for (int i = 0; i < 4; ++i) {
#pragma unroll
    for (int j = 0; j < 4; ++j) {
      int gr = m0 + wm * 64 + i * 16 + row4;
      int gc = n0 + wn * 64 + j * 16 + col16;
      float bv = bias[gc];
#pragma unroll
      for (int r = 0; r < 4; ++r)
        C[(size_t)(gr + r) * N + gc] = (OutT)(acc[i][j][r] + bv);
    }
  }
}

// ---------------- KV partial: kv_raw[bh,d,e] += sum_n exp(k[n,d]) v[n,e]; z_raw[bh,d] += sum_n exp(k[n,d]) ----------------
// grid (96, 8 splits), block 256. Each block: 512 rows in 8 chunks of 64.
__global__ __launch_bounds__(256) void kv_partial(const _Float16* __restrict__ kh,
                                                  const _Float16* __restrict__ vh,
                                                  float* __restrict__ kv_raw,
                                                  float* __restrict__ z_raw) {
  const int bh = blockIdx.x, b = bh / 12, h = bh % 12;
  const int split = blockIdx.y;
  __shared__ float ek_s[64][68];
  __shared__ float v_s[64][68];
  const int t = threadIdx.x;
  const int td = t >> 4, te = t & 15;
  const int d0 = td * 4, e0 = te * 4;
  const int zd = t & 63, zq = t >> 6;
  float acc[4][4] = {};
  float zp = 0.f;
  const size_t base = (size_t)b * 4096 * 768 + h * 64;

  for (int nc = 0; nc < 8; ++nc) {
    int n0 = split * 512 + nc * 64;
#pragma unroll
    for (int j = 0; j < 4; ++j) {
      int vi = t + j * 256;                 // 1024 vec4 loads cover 64x64
      int row = vi >> 4, c4 = (vi & 15) * 4;
      size_t g = base + (size_t)(n0 + row) * 768 + c4;
      f16x4 kv4 = *(const f16x4*)(kh + g);
      f16x4 vv4 = *(const f16x4*)(vh + g);
      f32x4 ek, vv;
      ek[0] = __expf((float)kv4[0]); ek[1] = __expf((float)kv4[1]);
      ek[2] = __expf((float)kv4[2]); ek[3] = __expf((float)kv4[3]);
      vv[0] = (float)vv4[0]; vv[1] = (float)vv4[1]; vv[2] = (float)vv4[2]; vv[3] = (float)vv4[3];
      *(f32x4*)&ek_s[row][c4] = ek;
      *(f32x4*)&v_s[row][c4] = vv;
    }
    __syncthreads();
#pragma unroll 4
    for (int r = 0; r < 16; ++r) zp += ek_s[zq * 16 + r][zd];
#pragma unroll 8
    for (int n = 0; n < 64; ++n) {
      f32x4 ekv = *(const f32x4*)&ek_s[n][d0];
      f32x4 vv  = *(const f32x4*)&v_s[n][e0];
#pragma unroll
      for (int i = 0; i < 4; ++i)
#pragma unroll
        for (int j = 0; j < 4; ++j)
          acc[i][j] += ekv[i] * vv[j];
    }
    __syncthreads();
  }
  float* kvp = kv_raw + (size_t)bh * 4096;
#pragma unroll
  for (int i = 0; i < 4; ++i)
#pragma unroll
    for (int j = 0; j < 4; ++j)
      atomicAdd(&kvp[(d0 + i) * 64 + e0 + j], acc[i][j]);
  atomicAdd(&z_raw[bh * 64 + zd], zp);
}

// ---------------- attn_out: att[n, h*64+e] = softmax_d(q[n, h*64+d]) @ kv[d,e] ----------------
// grid (96, 16), block 256 = 4 waves * 64 rows each. kv^T staged bf16 in LDS; per-16-row
// group: wave-wide softmax (lane=d) -> qrow LDS -> 2 A-frags -> 8 MFMA against hoisted B-frags.
__global__ __launch_bounds__(256) void attn_out(const _Float16* __restrict__ qh,
                                                const float* __restrict__ kv_raw,
                                                const float* __restrict__ z_raw,
                                                unsigned short* __restrict__ att) {
  const int bh = blockIdx.x, b = bh / 12, h = bh % 12;
  const int t = threadIdx.x, lane = t & 63, w = t >> 6;
  __shared__ unsigned short kvT[64][72];       // kvT[e][d] = kv[d][e], bf16, padded
  __shared__ unsigned short qrow[4][16][72];   // per-wave softmaxed q rows
  const float* kvp = kv_raw + (size_t)bh * 4096;
  const float* zp  = z_raw + bh * 64;
#pragma unroll
  for (int j = 0; j < 16; ++j) {
    int i = t + j * 256;
    int d = i >> 6, e = i & 63;
    float val = kvp[i] / (zp[d] * 8.0f);       // fold softmax-denominator and /sqrt(D)
    kvT[e][d] = f2bf(val);
  }
  __syncthreads();
  // hoist kv B-frags: B[k=d][col=e] -> read kvT[e][d] rows
  s16x8 bf[4][2];
#pragma unroll
  for (int j = 0; j < 4; ++j)
#pragma unroll
    for (int kk = 0; kk < 2; ++kk)
      bf[j][kk] = *(const s16x8*)&kvT[j * 16 + (lane & 15)][kk * 32 + (lane >> 4) * 8];

  const size_t qbase = (size_t)b * 4096 * 768 + h * 64;
  const int n_base = blockIdx.y * 256 + w * 64;
  for (int g = 0; g < 4; ++g) {
    int ng = n_base + g * 16;
    for (int r = 0; r < 16; ++r) {
      float ql = (float)qh[qbase + (size_t)(ng + r) * 768 + lane];
      float m = ql;
#pragma unroll
      for (int s = 32; s > 0; s >>= 1) m = fmaxf(m, __shfl_xor(m, s));
      float p = __expf(ql - m);
      float ssum = p;
#pragma unroll
      for (int s = 32; s > 0; s >>= 1) ssum += __shfl_xor(ssum, s);
      qrow[w][r][lane] = f2bf(p / ssum);
    }
    s16x8 af[2];
#pragma unroll
    for (int kk = 0; kk < 2; ++kk)
      af[kk] = *(const s16x8*)&qrow[w][lane & 15][kk * 32 + (lane >> 4) * 8];
#pragma unroll
    for (int j = 0; j < 4; ++j) {
      f32x4 o = {0.f, 0.f, 0.f, 0.f};
      o = __builtin_amdgcn_mfma_f32_16x16x32_bf16(af[0], bf[j][0], o, 0, 0, 0);
      o = __builtin_amdgcn_mfma_f32_16x16x32_bf16(af[1], bf[j][1], o, 0, 0, 0);
      int gc = h * 64 + j * 16 + (lane & 15);
#pragma unroll
      for (int r = 0; r < 4; ++r) {
        int gn = ng + (lane >> 4) * 4 + r;
        att[(size_t)(b * 4096 + gn) * 768 + gc] = f2bf(o[r]);
      }
    }
  }
}

// ---------------- launch ----------------
extern "C" void kernel_launch(void* const* d_in, const int* in_sizes, int n_in,
                              void* d_out, int out_size, void* d_ws, size_t ws_size,
                              hipStream_t stream) {
  const float* x  = (const float*)d_in[0];
  const float* Wq = (const float*)d_in[1];
  const float* bq = (const float*)d_in[2];
  const float* Wk = (const float*)d_in[3];
  const float* bk = (const float*)d_in[4];
  const float* Wv = (const float*)d_in[5];
  const float* bv = (const float*)d_in[6];
  const float* Wp = (const float*)d_in[7];
  const float* bp = (const float*)d_in[8];

  const size_t MT = 32768;          // B*N token rows
  const size_t XE = MT * 768;       // 25,165,824 elements
  const size_t WE = 768 * 768;      // 589,824

  unsigned short* x_bf  = (unsigned short*)d_ws;
  unsigned short* wq_bf = x_bf + XE;
  unsigned short* wk_bf = wq_bf + WE;
  unsigned short* wv_bf = wk_bf + WE;
  unsigned short* wp_bf = wv_bf + WE;
  _Float16* q_h = (_Float16*)(wp_bf + WE);
  _Float16* k_h = q_h + XE;
  _Float16* v_h = k_h + XE;
  unsigned short* att_bf = (unsigned short*)(v_h + XE);
  float* kv_raw = (float*)(att_bf + XE);
  float* z_raw  = kv_raw + 96 * 4096;
  // total ws usage: ~258 MB

  cast_f32_bf16<<<2048, 256, 0, stream>>>(x, x_bf, (int)(XE / 8));
  cast_f32_bf16<<<288, 256, 0, stream>>>(Wq, wq_bf, (int)(WE / 8));
  cast_f32_bf16<<<288, 256, 0, stream>>>(Wk, wk_bf, (int)(WE / 8));
  cast_f32_bf16<<<288, 256, 0, stream>>>(Wv, wv_bf, (int)(WE / 8));
  cast_f32_bf16<<<288, 256, 0, stream>>>(Wp, wp_bf, (int)(WE / 8));

  dim3 gg(6, 256, 1);
  gemm_bt<_Float16><<<gg, 256, 0, stream>>>(x_bf, wq_bf, bq, q_h, 768, 768);
  gemm_bt<_Float16><<<gg, 256, 0, stream>>>(x_bf, wk_bf, bk, k_h, 768, 768);
  gemm_bt<_Float16><<<gg, 256, 0, stream>>>(x_bf, wv_bf, bv, v_h, 768, 768);

  hipMemsetAsync(kv_raw, 0, (96 * 4096 + 96 * 64) * sizeof(float), stream);
  kv_partial<<<dim3(96, 8), 256, 0, stream>>>(k_h, v_h, kv_raw, z_raw);
  attn_out<<<dim3(96, 16), 256, 0, stream>>>(q_h, kv_raw, z_raw, att_bf);

  gemm_bt<float><<<gg, 256, 0, stream>>>(att_bf, wp_bf, bp, (float*)d_out, 768, 768);
}

// Round 2
// 418.210 us; speedup vs baseline: 1.1101x; 1.1101x over previous
//
#include <hip/hip_runtime.h>
#include <hip/hip_bf16.h>

// EfficientAttention: B=8 N=4096 C=768 H=12 D=64, M = B*N = 32768
// Stages: cast -> fused QKV GEMM (N=2304, fp16 out) -> KV/Z partial reduce
//         -> q-softmax @ kv (MFMA) -> out GEMM (fp32 + bias)
// GEMM: 128x128 tile, BK=64, 2-phase double-buffered LDS (stage-before-compute,
// counted-drain: one vmcnt(0)+s_barrier per K-step), T1 XCD swizzle m-major.

#define AS1 __attribute__((address_space(1)))
#define AS3 __attribute__((address_space(3)))

typedef __attribute__((ext_vector_type(8))) short    s16x8;
typedef __attribute__((ext_vector_type(4))) float    f32x4;
typedef __attribute__((ext_vector_type(4))) _Float16 f16x4;
typedef __attribute__((ext_vector_type(4))) unsigned short u16x4;

__device__ __forceinline__ unsigned short f2bf(float f) {
  union { float f; unsigned u; } v; v.f = f;
  unsigned r = v.u + 0x7FFFu + ((v.u >> 16) & 1u);   // round-to-nearest-even
  return (unsigned short)(r >> 16);
}

// ---------------- cast fp32 -> bf16 (vectorized 8/thread) ----------------
__global__ __launch_bounds__(256) void cast_f32_bf16(const float* __restrict__ src,
                                                     unsigned short* __restrict__ dst, int n8) {
  int stride = gridDim.x * blockDim.x;
  for (int i = blockIdx.x * blockDim.x + threadIdx.x; i < n8; i += stride) {
    const f32x4* s = (const f32x4*)(src + (size_t)i * 8);
    f32x4 a = s[0], b = s[1];
    u16x4 lo, hi;
    lo[0] = f2bf(a[0]); lo[1] = f2bf(a[1]); lo[2] = f2bf(a[2]); lo[3] = f2bf(a[3]);
    hi[0] = f2bf(b[0]); hi[1] = f2bf(b[1]); hi[2] = f2bf(b[2]); hi[3] = f2bf(b[3]);
    u16x4* d = (u16x4*)(dst + (size_t)i * 8);
    d[0] = lo; d[1] = hi;
  }
}

// cast 4 weights in one launch: Wq,Wk,Wv -> wqkv (contig), Wp -> wp
__global__ __launch_bounds__(256) void cast_w(const float* __restrict__ w0, const float* __restrict__ w1,
                                              const float* __restrict__ w2, const float* __restrict__ w3,
                                              unsigned short* __restrict__ dqkv,
                                              unsigned short* __restrict__ dp, int n8each) {
  int which = blockIdx.y;
  const float* s = (which == 0) ? w0 : (which == 1) ? w1 : (which == 2) ? w2 : w3;
  unsigned short* d = (which < 3) ? (dqkv + (size_t)which * n8each * 8) : dp;
  int stride = gridDim.x * blockDim.x;
  for (int i = blockIdx.x * blockDim.x + threadIdx.x; i < n8each; i += stride) {
    const f32x4* sv = (const f32x4*)(s + (size_t)i * 8);
    f32x4 a = sv[0], b = sv[1];
    u16x4 lo, hi;
    lo[0] = f2bf(a[0]); lo[1] = f2bf(a[1]); lo[2] = f2bf(a[2]); lo[3] = f2bf(a[3]);
    hi[0] = f2bf(b[0]); hi[1] = f2bf(b[1]); hi[2] = f2bf(b[2]); hi[3] = f2bf(b[3]);
    u16x4* dv = (u16x4*)(d + (size_t)i * 8);
    dv[0] = lo; dv[1] = hi;
  }
}

__global__ __launch_bounds__(256) void concat_bias(const float* __restrict__ bq, const float* __restrict__ bk,
                                                   const float* __restrict__ bv, float* __restrict__ dst) {
  int i = blockIdx.x * 256 + threadIdx.x;   // 0..2303
  if (i < 768) dst[i] = bq[i];
  else if (i < 1536) dst[i] = bk[i - 768];
  else if (i < 2304) dst[i] = bv[i - 1536];
}

// ---------------- GEMM: C[M,N] = A[M,K] * B[N,K]^T + bias ----------------
// 2-phase dbuf: STAGE(next) issued before ds_read+MFMA(cur); single counted
// drain vmcnt(0) + raw s_barrier per K-step so staging flies under the MFMAs.
// T1: bijective XCD swizzle, m-major logical order (A-panel reuse in L2).
template <typename OutT>
__global__ __launch_bounds__(256) void gemm_bt(const unsigned short* __restrict__ A,
                                               const unsigned short* __restrict__ Bm,
                                               const float* __restrict__ bias,
                                               OutT* __restrict__ C,
                                               int N, int K, int nb) {
  __shared__ unsigned short As[2][128 * 64];
  __shared__ unsigned short Bs[2][128 * 64];
  const int tid = threadIdx.x, lane = tid & 63, wid = tid >> 6;
  const int wm = wid >> 1, wn = wid & 1;
  // T1 swizzle: XCD b%8 gets a contiguous logical chunk; logical is m-major.
  const int cpx = gridDim.x >> 3;
  const int logical = (blockIdx.x & 7) * cpx + (blockIdx.x >> 3);
  const int m0 = (logical / nb) * 128, n0 = (logical % nb) * 128;
  f32x4 acc[4][4] = {};
  const int srow = lane >> 3;            // 0..7 within 8-row chunk
  const int scol = (lane & 7) * 8;       // 8 bf16 = 16B per lane

  auto stage = [&](int buf, int k0) {
#pragma unroll
    for (int c = 0; c < 4; ++c) {
      int chunk = c * 4 + wid;                 // 16 chunks of 1KB per 16KB tile
      int row = chunk * 8 + srow;
      __builtin_amdgcn_global_load_lds(
          (const AS1 void*)(A + (size_t)(m0 + row) * K + k0 + scol),
          (AS3 void*)(&As[buf][chunk * 512]), 16, 0, 0);
      __builtin_amdgcn_global_load_lds(
          (const AS1 void*)(Bm + (size_t)(n0 + row) * K + k0 + scol),
          (AS3 void*)(&Bs[buf][chunk * 512]), 16, 0, 0);
    }
  };

  stage(0, 0);
  asm volatile("s_waitcnt vmcnt(0)" ::: "memory");
  __builtin_amdgcn_s_barrier();

  const int nsteps = K >> 6;
  int cur = 0;
  for (int s = 0; s < nsteps; ++s) {
    if (s + 1 < nsteps) stage(cur ^ 1, (s + 1) << 6);   // fly during MFMA phase
    const unsigned short* Ab = &As[cur][0];
    const unsigned short* Bb = &Bs[cur][0];
#pragma unroll
    for (int kk = 0; kk < 64; kk += 32) {
      s16x8 af[4], bf[4];
#pragma unroll
      for (int i = 0; i < 4; ++i)
        af[i] = *(const s16x8*)(Ab + (wm * 64 + i * 16 + (lane & 15)) * 64 + kk + (lane >> 4) * 8);
#pragma unroll
      for (int j = 0; j < 4; ++j)
        bf[j] = *(const s16x8*)(Bb + (wn * 64 + j * 16 + (lane & 15)) * 64 + kk + (lane >> 4) * 8);
#pragma unroll
      for (int i = 0; i < 4; ++i)
#pragma unroll
        for (int j = 0; j < 4; ++j)
          acc[i][j] = __builtin_amdgcn_mfma_f32_16x16x32_bf16(af[i], bf[j], acc[i][j], 0, 0, 0);
    }
    asm volatile("s_waitcnt vmcnt(0)" ::: "memory");  // staging for s+1 had full MFMA phase to land
    __builtin_amdgcn_s_barrier();
    cur ^= 1;
  }
  // epilogue: C/D layout col=lane&15, row=(lane>>4)*4+reg  [m89/m91-verified]
  const int col16 = lane & 15, row4 = (lane >> 4) * 4;
#pragma unroll
  for (int i = 0; i < 4; ++i) {
#pragma unroll
    for (int j = 0; j < 4; ++j) {
      int gr = m0 + wm * 64 + i * 16 + row4;
      int gc = n0 + wn * 64 + j * 16 + col16;
      float bv = bias[gc];
#pragma unroll
      for (int r = 0; r < 4; ++r)
        C[(size_t)(gr + r) * N + gc] = (OutT)(acc[i][j][r] + bv);
    }
  }
}

// ---------------- KV partial: kv_raw[bh,d,e] += sum_n exp(k[n,d]) v[n,e]; z_raw[bh,d] += sum_n exp(k[n,d]) ----------------
// k/v live in the fused qkv buffer: row stride 2304, kh/vh pre-offset to their column block.
__global__ __launch_bounds__(256) void kv_partial(const _Float16* __restrict__ kh,
                                                  const _Float16* __restrict__ vh,
                                                  float* __restrict__ kv_raw,
                                                  float* __restrict__ z_raw) {
  const int bh = blockIdx.x, b = bh / 12, h = bh % 12;
  const int split = blockIdx.y;
  __shared__ float ek_s[64][68];
  __shared__ float v_s[64][68];
  const int t = threadIdx.x;
  const int td = t >> 4, te = t & 15;
  const int d0 = td * 4, e0 = te * 4;
  const int zd = t & 63, zq = t >> 6;
  float acc[4][4] = {};
  float zp = 0.f;
  const size_t base = (size_t)b * 4096 * 2304 + h * 64;

  for (int nc = 0; nc < 8; ++nc) {
    int n0 = split * 512 + nc * 64;
#pragma unroll
    for (int j = 0; j < 4; ++j) {
      int vi = t + j * 256;                 // 1024 vec4 loads cover 64x64
      int row = vi >> 4, c4 = (vi & 15) * 4;
      size_t g = base + (size_t)(n0 + row) * 2304 + c4;
      f16x4 kv4 = *(const f16x4*)(kh + g);
      f16x4 vv4 = *(const f16x4*)(vh + g);
      f32x4 ek, vv;
      ek[0] = __expf((float)kv4[0]); ek[1] = __expf((float)kv4[1]);
      ek[2] = __expf((float)kv4[2]); ek[3] = __expf((float)kv4[3]);
      vv[0] = (float)vv4[0]; vv[1] = (float)vv4[1]; vv[2] = (float)vv4[2]; vv[3] = (float)vv4[3];
      *(f32x4*)&ek_s[row][c4] = ek;
      *(f32x4*)&v_s[row][c4] = vv;
    }
    __syncthreads();
#pragma unroll 4
    for (int r = 0; r < 16; ++r) zp += ek_s[zq * 16 + r][zd];
#pragma unroll 8
    for (int n = 0; n < 64; ++n) {
      f32x4 ekv = *(const f32x4*)&ek_s[n][d0];
      f32x4 vv  = *(const f32x4*)&v_s[n][e0];
#pragma unroll
      for (int i = 0; i < 4; ++i)
#pragma unroll
        for (int j = 0; j < 4; ++j)
          acc[i][j] += ekv[i] * vv[j];
    }
    __syncthreads();
  }
  float* kvp = kv_raw + (size_t)bh * 4096;
#pragma unroll
  for (int i = 0; i < 4; ++i)
#pragma unroll
    for (int j = 0; j < 4; ++j)
      atomicAdd(&kvp[(d0 + i) * 64 + e0 + j], acc[i][j]);
  atomicAdd(&z_raw[bh * 64 + zd], zp);
}

// ---------------- attn_out: att[n, h*64+e] = softmax_d(q[n,·]) @ kv[d,e] ----------------
__global__ __launch_bounds__(256) void attn_out(const _Float16* __restrict__ qh,
                                                const float* __restrict__ kv_raw,
                                                const float* __restrict__ z_raw,
                                                unsigned short* __restrict__ att) {
  const int bh = blockIdx.x, b = bh / 12, h = bh % 12;
  const int t = threadIdx.x, lane = t & 63, w = t >> 6;
  __shared__ unsigned short kvT[64][72];       // kvT[e][d] = kv[d][e], bf16, padded
  __shared__ unsigned short qrow[4][16][72];   // per-wave softmaxed q rows
  const float* kvp = kv_raw + (size_t)bh * 4096;
  const float* zp  = z_raw + bh * 64;
#pragma unroll
  for (int j = 0; j < 16; ++j) {
    int i = t + j * 256;
    int d = i >> 6, e = i & 63;
    float val = kvp[i] / (zp[d] * 8.0f);       // fold softmax denom and /sqrt(D)
    kvT[e][d] = f2bf(val);
  }
  __syncthreads();
  s16x8 bf[4][2];
#pragma unroll
  for (int j = 0; j < 4; ++j)
#pragma unroll
    for (int kk = 0; kk < 2; ++kk)
      bf[j][kk] = *(const s16x8*)&kvT[j * 16 + (lane & 15)][kk * 32 + (lane >> 4) * 8];

  const size_t qbase = (size_t)b * 4096 * 2304 + h * 64;
  const int n_base = blockIdx.y * 256 + w * 64;
  for (int g = 0; g < 4; ++g) {
    int ng = n_base + g * 16;
    for (int r = 0; r < 16; ++r) {
      float ql = (float)qh[qbase + (size_t)(ng + r) * 2304 + lane];
      float m = ql;
#pragma unroll
      for (int s = 32; s > 0; s >>= 1) m = fmaxf(m, __shfl_xor(m, s));
      float p = __expf(ql - m);
      float ssum = p;
#pragma unroll
      for (int s = 32; s > 0; s >>= 1) ssum += __shfl_xor(ssum, s);
      qrow[w][r][lane] = f2bf(p / ssum);
    }
    s16x8 af[2];
#pragma unroll
    for (int kk = 0; kk < 2; ++kk)
      af[kk] = *(const s16x8*)&qrow[w][lane & 15][kk * 32 + (lane >> 4) * 8];
#pragma unroll
    for (int j = 0; j < 4; ++j) {
      f32x4 o = {0.f, 0.f, 0.f, 0.f};
      o = __builtin_amdgcn_mfma_f32_16x16x32_bf16(af[0], bf[j][0], o, 0, 0, 0);
      o = __builtin_amdgcn_mfma_f32_16x16x32_bf16(af[1], bf[j][1], o, 0, 0, 0);
      int gc = h * 64 + j * 16 + (lane & 15);
#pragma unroll
      for (int r = 0; r < 4; ++r) {
        int gn = ng + (lane >> 4) * 4 + r;
        att[(size_t)(b * 4096 + gn) * 768 + gc] = f2bf(o[r]);
      }
    }
  }
}

// ---------------- launch ----------------
extern "C" void kernel_launch(void* const* d_in, const int* in_sizes, int n_in,
                              void* d_out, int out_size, void* d_ws, size_t ws_size,
                              hipStream_t stream) {
  const float* x  = (const float*)d_in[0];
  const float* Wq = (const float*)d_in[1];
  const float* bq = (const float*)d_in[2];
  const float* Wk = (const float*)d_in[3];
  const float* bk = (const float*)d_in[4];
  const float* Wv = (const float*)d_in[5];
  const float* bv = (const float*)d_in[6];
  const float* Wp = (const float*)d_in[7];
  const float* bp = (const float*)d_in[8];

  const size_t MT = 32768;          // B*N token rows
  const size_t XE = MT * 768;       // 25,165,824
  const size_t WE = 768 * 768;      // 589,824

  unsigned short* x_bf    = (unsigned short*)d_ws;
  unsigned short* wqkv_bf = x_bf + XE;            // [2304][768]
  unsigned short* wp_bf   = wqkv_bf + 3 * WE;
  _Float16* qkv_h = (_Float16*)(wp_bf + WE);      // [32768][2304]: q|k|v
  unsigned short* att_bf = (unsigned short*)(qkv_h + MT * 2304);
  float* bqkv   = (float*)(att_bf + XE);          // 2304
  float* kv_raw = bqkv + 2304;                    // 96*4096
  float* z_raw  = kv_raw + 96 * 4096;             // 96*64

  cast_f32_bf16<<<2048, 256, 0, stream>>>(x, x_bf, (int)(XE / 8));
  cast_w<<<dim3(288, 4), 256, 0, stream>>>(Wq, Wk, Wv, Wp, wqkv_bf, wp_bf, (int)(WE / 8));
  concat_bias<<<9, 256, 0, stream>>>(bq, bk, bv, bqkv);

  // fused QKV GEMM: [32768,768] x [2304,768]^T -> fp16 [32768,2304]
  gemm_bt<_Float16><<<4608, 256, 0, stream>>>(x_bf, wqkv_bf, bqkv, qkv_h, 2304, 768, 18);

  hipMemsetAsync(kv_raw, 0, (96 * 4096 + 96 * 64) * sizeof(float), stream);
  kv_partial<<<dim3(96, 8), 256, 0, stream>>>(qkv_h + 768, qkv_h + 1536, kv_raw, z_raw);
  attn_out<<<dim3(96, 16), 256, 0, stream>>>(qkv_h, kv_raw, z_raw, att_bf);

  // out projection: [32768,768] x [768,768]^T + bp -> fp32 d_out
  gemm_bt<float><<<1536, 256, 0, stream>>>(att_bf, wp_bf, bp, (float*)d_out, 768, 768, 6);
}

// Round 3
// 365.160 us; speedup vs baseline: 1.2714x; 1.1453x over previous
//
#include <hip/hip_runtime.h>
#include <hip/hip_bf16.h>

// EfficientAttention: B=8 N=4096 C=768 H=12 D=64, M = 32768
// cast -> gemm256<QKV> (q-softmax fused epilogue; k,v fp16) -> kv_partial
//      -> weff_build (kv_n @ Wp^T per head, folds attn_out+out-proj B) -> gemm256<OUT>
// gemm256: 256x256 tile, BK=64, 8 waves, 4 quadrant-phases/tile, dbuf LDS 128KiB,
// counted vmcnt(8) gate once per K-tile (T4), T2 source-side XOR swizzle, T5 setprio,
// T1 bijective XCD swizzle (m-major).

#define AS1 __attribute__((address_space(1)))
#define AS3 __attribute__((address_space(3)))

typedef __attribute__((ext_vector_type(8))) short    s16x8;
typedef __attribute__((ext_vector_type(4))) float    f32x4;
typedef __attribute__((ext_vector_type(4))) _Float16 f16x4;
typedef __attribute__((ext_vector_type(4))) unsigned short u16x4;

__device__ __forceinline__ unsigned short f2bf(float f) {
  union { float f; unsigned u; } v; v.f = f;
  unsigned r = v.u + 0x7FFFu + ((v.u >> 16) & 1u);
  return (unsigned short)(r >> 16);
}

// ---------------- casts ----------------
__global__ __launch_bounds__(256) void cast_f32_bf16(const float* __restrict__ src,
                                                     unsigned short* __restrict__ dst, int n8) {
  int stride = gridDim.x * blockDim.x;
  for (int i = blockIdx.x * blockDim.x + threadIdx.x; i < n8; i += stride) {
    const f32x4* s = (const f32x4*)(src + (size_t)i * 8);
    f32x4 a = s[0], b = s[1];
    u16x4 lo, hi;
    lo[0] = f2bf(a[0]); lo[1] = f2bf(a[1]); lo[2] = f2bf(a[2]); lo[3] = f2bf(a[3]);
    hi[0] = f2bf(b[0]); hi[1] = f2bf(b[1]); hi[2] = f2bf(b[2]); hi[3] = f2bf(b[3]);
    u16x4* d = (u16x4*)(dst + (size_t)i * 8);
    d[0] = lo; d[1] = hi;
  }
}

__global__ __launch_bounds__(256) void cast_w3(const float* __restrict__ w0, const float* __restrict__ w1,
                                               const float* __restrict__ w2,
                                               unsigned short* __restrict__ dqkv, int n8each) {
  int which = blockIdx.y;
  const float* s = (which == 0) ? w0 : (which == 1) ? w1 : w2;
  unsigned short* d = dqkv + (size_t)which * n8each * 8;
  int stride = gridDim.x * blockDim.x;
  for (int i = blockIdx.x * blockDim.x + threadIdx.x; i < n8each; i += stride) {
    const f32x4* sv = (const f32x4*)(s + (size_t)i * 8);
    f32x4 a = sv[0], b = sv[1];
    u16x4 lo, hi;
    lo[0] = f2bf(a[0]); lo[1] = f2bf(a[1]); lo[2] = f2bf(a[2]); lo[3] = f2bf(a[3]);
    hi[0] = f2bf(b[0]); hi[1] = f2bf(b[1]); hi[2] = f2bf(b[2]); hi[3] = f2bf(b[3]);
    u16x4* dv = (u16x4*)(d + (size_t)i * 8);
    dv[0] = lo; dv[1] = hi;
  }
}

__global__ __launch_bounds__(256) void concat_bias(const float* __restrict__ bq, const float* __restrict__ bk,
                                                   const float* __restrict__ bv, float* __restrict__ dst) {
  int i = blockIdx.x * 256 + threadIdx.x;
  if (i < 768) dst[i] = bq[i];
  else if (i < 1536) dst[i] = bk[i - 768];
  else if (i < 2304) dst[i] = bv[i - 1536];
}

// ---------------- gemm256: C[M,N] = A[M,K] @ Bm[N,K]^T + bias ----------------
// MODE 0: fp32 out (out-proj; Bm batched per 4096 rows). MODE 1: QKV epilogue.
template <int MODE>
__global__ __launch_bounds__(512, 2) void gemm256(const unsigned short* __restrict__ A,
                                                  const unsigned short* __restrict__ Bm,
                                                  const float* __restrict__ bias,
                                                  void* out0, void* out1, void* out2,
                                                  int N, int K, int nb, int batchedB) {
  __shared__ unsigned short As[2][2][128][64];   // [buf][half][lrow][col8*8]
  __shared__ unsigned short Bs[2][2][128][64];
  const int tid = threadIdx.x, lane = tid & 63, wid = tid >> 6;
  const int wr = wid >> 2, wc = wid & 3;         // 2 x 4 waves
  const int cpx = gridDim.x >> 3;
  const int logical = (blockIdx.x & 7) * cpx + (blockIdx.x >> 3);
  const int m0 = (logical / nb) * 256, n0 = (logical % nb) * 256;
  const unsigned short* Bp = Bm + (batchedB ? ((size_t)(m0 >> 12) * 589824) : 0);

  f32x4 acc[8][4] = {};
  const int srcc8 = ((lane & 7) ^ (lane >> 3)) * 8;   // pre-swizzled global col (T2, rule 21)

  // stage units: 2 x global_load_lds(16B) per thread each; region = consumption unit
  auto stageA = [&](int buf, int which, int k0) {     // which: 0 = lrow 0-63, 1 = 64-127 (both halves)
#pragma unroll
    for (int half = 0; half < 2; ++half) {
      int lrow = which * 64 + (tid >> 3);
      __builtin_amdgcn_global_load_lds(
          (const AS1 void*)(A + (size_t)(m0 + half * 128 + lrow) * K + k0 + srcc8),
          (AS3 void*)(&As[buf][half][lrow][(tid & 7) * 8]), 16, 0, 0);
    }
  };
  auto stageB = [&](int buf, int which, int k0) {     // which 0: rows {0-31,64-95}; 1: {32-63,96-127}
#pragma unroll
    for (int j = 0; j < 2; ++j) {
      int idx = tid + j * 512;
      int half = idx >> 9, sub = (idx >> 8) & 1;
      int lrow = sub * 64 + which * 32 + ((idx & 255) >> 3);
      __builtin_amdgcn_global_load_lds(
          (const AS1 void*)(Bp + (size_t)(n0 + half * 128 + lrow) * K + k0 + srcc8),
          (AS3 void*)(&Bs[buf][half][lrow][(idx & 7) * 8]), 16, 0, 0);
    }
  };

  const int r15 = lane & 15, hi8 = (lane >> 4) * 8, sw = (lane & 7) * 8;
  s16x8 af[4][2], bf[4][2];
  auto readA = [&](int buf, int grp) {   // grp 0: mi 0-3 ; grp 1: mi 4-7  (8 x ds_read_b128)
    const unsigned short* base = &As[buf][wr][0][0];
#pragma unroll
    for (int i = 0; i < 4; ++i) {
      int lrow = (grp * 4 + i) * 16 + r15;
#pragma unroll
      for (int kk = 0; kk < 2; ++kk)
        af[i][kk] = *(const s16x8*)(base + lrow * 64 + ((kk * 32 + hi8) ^ sw));
    }
  };
  auto readB = [&](int buf, int grp) {   // grp 0: j 0-1 ; grp 1: j 2-3  (4 x ds_read_b128)
    const unsigned short* base = &Bs[buf][wc >> 1][0][0];
#pragma unroll
    for (int jj = 0; jj < 2; ++jj) {
      int j = grp * 2 + jj;
      int lrow = (wc & 1) * 64 + j * 16 + r15;
#pragma unroll
      for (int kk = 0; kk < 2; ++kk)
        bf[j][kk] = *(const s16x8*)(base + lrow * 64 + ((kk * 32 + hi8) ^ sw));
    }
  };

#define MFMA16(MI0, J0)                                                             \
  __builtin_amdgcn_s_setprio(1);                                                    \
  _Pragma("unroll") for (int i = 0; i < 4; ++i)                                     \
  _Pragma("unroll") for (int jj = 0; jj < 2; ++jj)                                  \
  _Pragma("unroll") for (int kk = 0; kk < 2; ++kk)                                  \
    acc[(MI0) + i][(J0) + jj] = __builtin_amdgcn_mfma_f32_16x16x32_bf16(            \
        af[i][kk], bf[(J0) + jj][kk], acc[(MI0) + i][(J0) + jj], 0, 0, 0);          \
  __builtin_amdgcn_s_setprio(0);

  // prologue: tiles 0,1 (8 loads each); gate tile0 with vmcnt(8)
  stageA(0, 0, 0);  stageA(0, 1, 0);  stageB(0, 0, 0);  stageB(0, 1, 0);
  stageA(1, 0, 64); stageA(1, 1, 64); stageB(1, 0, 64); stageB(1, 1, 64);
  asm volatile("s_waitcnt vmcnt(8)" ::: "memory");
  __builtin_amdgcn_s_barrier();

  const int nt = K >> 6;
  for (int s = 0; s < nt; ++s) {
    const int buf = s & 1;
    const int k2 = (s + 2) << 6;
    const bool pf = (s + 2) < nt;
    // P1: ds_read A_lo + B_lo ; MFMA Q(mi0-3, j0-1)
    readA(buf, 0);
    readB(buf, 0);
    asm volatile("" ::: "memory");
    __builtin_amdgcn_s_barrier();
    asm volatile("s_waitcnt lgkmcnt(0)" ::: "memory");
    __builtin_amdgcn_sched_barrier(0);
    MFMA16(0, 0)
    asm volatile("" ::: "memory");
    __builtin_amdgcn_s_barrier();
    // P2: ds_read B_hi ; stage A_lo,B_lo(s+2) ; MFMA Q(mi0-3, j2-3)
    readB(buf, 1);
    if (pf) { stageA(buf, 0, k2); stageB(buf, 0, k2); }
    asm volatile("" ::: "memory");
    __builtin_amdgcn_s_barrier();
    asm volatile("s_waitcnt lgkmcnt(0)" ::: "memory");
    __builtin_amdgcn_sched_barrier(0);
    MFMA16(0, 2)
    asm volatile("" ::: "memory");
    __builtin_amdgcn_s_barrier();
    // P3: ds_read A_hi ; stage B_hi(s+2) ; MFMA Q(mi4-7, j2-3)
    readA(buf, 1);
    if (pf) stageB(buf, 1, k2);
    asm volatile("" ::: "memory");
    __builtin_amdgcn_s_barrier();
    asm volatile("s_waitcnt lgkmcnt(0)" ::: "memory");
    __builtin_amdgcn_sched_barrier(0);
    MFMA16(4, 2)
    asm volatile("" ::: "memory");
    __builtin_amdgcn_s_barrier();
    // P4: stage A_hi(s+2) ; MFMA Q(mi4-7, j0-1) ; counted gate ; barrier
    if (pf) stageA(buf, 1, k2);
    MFMA16(4, 0)
    if (pf)                asm volatile("s_waitcnt vmcnt(8)" ::: "memory");
    else if (s + 1 < nt)   asm volatile("s_waitcnt vmcnt(0)" ::: "memory");
    __builtin_amdgcn_s_barrier();
  }

  // ---------------- epilogue ----------------
  const int g = lane >> 4, c15 = lane & 15;
  float bj[4];
#pragma unroll
  for (int j = 0; j < 4; ++j) bj[j] = bias[n0 + wc * 64 + j * 16 + c15];

  if (MODE == 0) {
    float* out = (float*)out0;
#pragma unroll
    for (int mi = 0; mi < 8; ++mi)
#pragma unroll
      for (int j = 0; j < 4; ++j) {
        int gr = m0 + wr * 128 + mi * 16 + g * 4;
        int gc = n0 + wc * 64 + j * 16 + c15;
#pragma unroll
        for (int r = 0; r < 4; ++r)
          out[(size_t)(gr + r) * N + gc] = acc[mi][j][r] + bj[j];
      }
  } else {
    if (n0 < 768) {                      // q block: per-row softmax over this wave's 64 cols (one head)
      unsigned short* qsm = (unsigned short*)out0;
      const int cbase = n0 + wc * 64;
#pragma unroll
      for (int mi = 0; mi < 8; ++mi) {
#pragma unroll
        for (int r = 0; r < 4; ++r) {
          int gr = m0 + wr * 128 + mi * 16 + g * 4 + r;
          float v[4];
#pragma unroll
          for (int j = 0; j < 4; ++j) v[j] = acc[mi][j][r] + bj[j];
          float mx = fmaxf(fmaxf(v[0], v[1]), fmaxf(v[2], v[3]));
#pragma unroll
          for (int st = 1; st < 16; st <<= 1) mx = fmaxf(mx, __shfl_xor(mx, st));
          float p[4], sm = 0.f;
#pragma unroll
          for (int j = 0; j < 4; ++j) { p[j] = __expf(v[j] - mx); sm += p[j]; }
#pragma unroll
          for (int st = 1; st < 16; st <<= 1) sm += __shfl_xor(sm, st);
          float inv = 1.0f / sm;
#pragma unroll
          for (int j = 0; j < 4; ++j)
            qsm[(size_t)gr * 768 + cbase + j * 16 + c15] = f2bf(p[j] * inv);
        }
      }
    } else {                             // k or v block: fp16 compact store
      _Float16* dst = (n0 < 1536) ? (_Float16*)out1 : (_Float16*)out2;
      const int cbase = (n0 < 1536 ? n0 - 768 : n0 - 1536) + wc * 64;
#pragma unroll
      for (int mi = 0; mi < 8; ++mi)
#pragma unroll
        for (int j = 0; j < 4; ++j) {
          int gr = m0 + wr * 128 + mi * 16 + g * 4;
          int cc = cbase + j * 16 + c15;
#pragma unroll
          for (int r = 0; r < 4; ++r)
            dst[(size_t)(gr + r) * 768 + cc] = (_Float16)(acc[mi][j][r] + bj[j]);
        }
    }
  }
#undef MFMA16
}

// ---------------- KV partial: kv_raw[bh,d,e] += sum_n exp(k[n,d]) v[n,e]; z += sum exp(k) ----------------
__global__ __launch_bounds__(256) void kv_partial(const _Float16* __restrict__ kh,
                                                  const _Float16* __restrict__ vh,
                                                  float* __restrict__ kv_raw,
                                                  float* __restrict__ z_raw) {
  const int bh = blockIdx.x, b = bh / 12, h = bh % 12;
  const int split = blockIdx.y;
  __shared__ float ek_s[64][68];
  __shared__ float v_s[64][68];
  const int t = threadIdx.x;
  const int d0 = (t >> 4) * 4, e0 = (t & 15) * 4;
  const int zd = t & 63, zq = t >> 6;
  float acc[4][4] = {};
  float zp = 0.f;
  const size_t base = (size_t)b * 4096 * 768 + h * 64;

  for (int nc = 0; nc < 8; ++nc) {
    int n0 = split * 512 + nc * 64;
#pragma unroll
    for (int j = 0; j < 4; ++j) {
      int vi = t + j * 256;
      int row = vi >> 4, c4 = (vi & 15) * 4;
      size_t gp = base + (size_t)(n0 + row) * 768 + c4;
      f16x4 kv4 = *(const f16x4*)(kh + gp);
      f16x4 vv4 = *(const f16x4*)(vh + gp);
      f32x4 ek, vv;
      ek[0] = __expf((float)kv4[0]); ek[1] = __expf((float)kv4[1]);
      ek[2] = __expf((float)kv4[2]); ek[3] = __expf((float)kv4[3]);
      vv[0] = (float)vv4[0]; vv[1] = (float)vv4[1]; vv[2] = (float)vv4[2]; vv[3] = (float)vv4[3];
      *(f32x4*)&ek_s[row][c4] = ek;
      *(f32x4*)&v_s[row][c4] = vv;
    }
    __syncthreads();
#pragma unroll 4
    for (int r = 0; r < 16; ++r) zp += ek_s[zq * 16 + r][zd];
#pragma unroll 8
    for (int n = 0; n < 64; ++n) {
      f32x4 ekv = *(const f32x4*)&ek_s[n][d0];
      f32x4 vv  = *(const f32x4*)&v_s[n][e0];
#pragma unroll
      for (int i = 0; i < 4; ++i)
#pragma unroll
        for (int j = 0; j < 4; ++j)
          acc[i][j] += ekv[i] * vv[j];
    }
    __syncthreads();
  }
  float* kvp = kv_raw + (size_t)bh * 4096;
#pragma unroll
  for (int i = 0; i < 4; ++i)
#pragma unroll
    for (int j = 0; j < 4; ++j)
      atomicAdd(&kvp[(d0 + i) * 64 + e0 + j], acc[i][j]);
  atomicAdd(&z_raw[bh * 64 + zd], zp);
}

// ---------------- Weff: weffT[b][c][h*64+d] = sum_e kv_n[b,h,d,e] * Wp[c][h*64+e] ----------------
__global__ __launch_bounds__(256) void weff_build(const float* __restrict__ kv_raw,
                                                  const float* __restrict__ z_raw,
                                                  const float* __restrict__ Wp,
                                                  unsigned short* __restrict__ weffT) {
  const int c0 = blockIdx.x * 64, h = blockIdx.y, b = blockIdx.z;
  const int bh = b * 12 + h;
  __shared__ float kvn[64][65];
  const int t = threadIdx.x;
#pragma unroll
  for (int i = 0; i < 16; ++i) {
    int idx = t + i * 256;
    int d = idx >> 6;
    kvn[d][idx & 63] = kv_raw[(size_t)bh * 4096 + idx] / (z_raw[bh * 64 + d] * 8.0f);
  }
  __syncthreads();
  const int c = c0 + (t >> 2);
  const int d0 = (t & 3) * 16;
  const float* wrow = Wp + (size_t)c * 768 + h * 64;
  float acc[16] = {};
#pragma unroll 8
  for (int e = 0; e < 64; ++e) {
    float w = wrow[e];
#pragma unroll
    for (int dd = 0; dd < 16; ++dd) acc[dd] += w * kvn[d0 + dd][e];
  }
  unsigned short* orow = weffT + (size_t)b * 589824 + (size_t)c * 768 + h * 64 + d0;
#pragma unroll
  for (int dd = 0; dd < 16; ++dd) orow[dd] = f2bf(acc[dd]);
}

// ---------------- launch ----------------
extern "C" void kernel_launch(void* const* d_in, const int* in_sizes, int n_in,
                              void* d_out, int out_size, void* d_ws, size_t ws_size,
                              hipStream_t stream) {
  const float* x  = (const float*)d_in[0];
  const float* Wq = (const float*)d_in[1];
  const float* bq = (const float*)d_in[2];
  const float* Wk = (const float*)d_in[3];
  const float* bk = (const float*)d_in[4];
  const float* Wv = (const float*)d_in[5];
  const float* bv = (const float*)d_in[6];
  const float* Wp = (const float*)d_in[7];
  const float* bp = (const float*)d_in[8];

  const size_t MT = 32768;
  const size_t XE = MT * 768;       // 25,165,824
  const size_t WE = 768 * 768;

  unsigned short* x_bf    = (unsigned short*)d_ws;          // 48 MB
  unsigned short* wqkv_bf = x_bf + XE;                       // 3.4 MB
  unsigned short* q_sm    = wqkv_bf + 3 * WE;                // 48 MB (bf16, softmaxed q)
  _Float16* k_h = (_Float16*)(q_sm + XE);                    // 48 MB
  _Float16* v_h = k_h + XE;                                  // 48 MB
  unsigned short* weffT = (unsigned short*)(v_h + XE);       // 9.4 MB (bf16 [8][768][768])
  float* bqkv   = (float*)(weffT + 8 * WE);                  // 2304
  float* kv_raw = bqkv + 2304;                               // 96*4096
  float* z_raw  = kv_raw + 96 * 4096;                        // 96*64

  cast_f32_bf16<<<2048, 256, 0, stream>>>(x, x_bf, (int)(XE / 8));
  cast_w3<<<dim3(288, 3), 256, 0, stream>>>(Wq, Wk, Wv, wqkv_bf, (int)(WE / 8));
  concat_bias<<<9, 256, 0, stream>>>(bq, bk, bv, bqkv);
  hipMemsetAsync(kv_raw, 0, (96 * 4096 + 96 * 64) * sizeof(float), stream);

  // fused QKV GEMM: [32768,768] x [2304,768]^T ; epilogue: q-softmax->bf16, k/v->fp16
  gemm256<1><<<1152, 512, 0, stream>>>(x_bf, wqkv_bf, bqkv, q_sm, k_h, v_h, 2304, 768, 9, 0);

  kv_partial<<<dim3(96, 8), 256, 0, stream>>>(k_h, v_h, kv_raw, z_raw);
  weff_build<<<dim3(12, 12, 8), 256, 0, stream>>>(kv_raw, z_raw, Wp, weffT);

  // out = q_sm @ Weff_b^T + bp  (batched B per 4096 rows)
  gemm256<0><<<384, 512, 0, stream>>>(q_sm, weffT, bp, d_out, nullptr, nullptr, 768, 768, 3, 1);
}

// Round 4
// 356.341 us; speedup vs baseline: 1.3029x; 1.0248x over previous
//
#include <hip/hip_runtime.h>
#include <hip/hip_bf16.h>

// EfficientAttention: B=8 N=4096 C=768 H=12 D=64, M = 32768
// prep (cast x,Wqkv + bias concat) -> gemm256<QKV,BM256> (q-softmax epilogue; k,v fp16)
//   -> kv_partial -> weff_build -> gemm256<OUT,BM128> (fp32 + bias)
// gemm256: BK=64, 8 waves, dbuf LDS, counted vmcnt gate once per K-tile (T4),
// T2 source-side XOR swizzle (0 conflicts verified R3), T5 setprio, T1 XCD swizzle.
// R4: kk-OUTER mfma order (dep distance 8, was back-to-back dependent pairs),
//     sched_barrier(0) removed (m141), out-proj BM=128 (3 clean rounds).

#define AS1 __attribute__((address_space(1)))
#define AS3 __attribute__((address_space(3)))

typedef __attribute__((ext_vector_type(8))) short    s16x8;
typedef __attribute__((ext_vector_type(4))) float    f32x4;
typedef __attribute__((ext_vector_type(8))) _Float16 f16x8;
typedef __attribute__((ext_vector_type(4))) unsigned short u16x4;

__device__ __forceinline__ unsigned short f2bf(float f) {
  union { float f; unsigned u; } v; v.f = f;
  unsigned r = v.u + 0x7FFFu + ((v.u >> 16) & 1u);
  return (unsigned short)(r >> 16);
}

// ---------------- prep: cast x + Wq|Wk|Wv -> bf16, concat bias ----------------
__global__ __launch_bounds__(256) void prep(const float* __restrict__ x,
                                            const float* __restrict__ Wq, const float* __restrict__ Wk,
                                            const float* __restrict__ Wv,
                                            const float* __restrict__ bq, const float* __restrict__ bk,
                                            const float* __restrict__ bv,
                                            unsigned short* __restrict__ x_bf,
                                            unsigned short* __restrict__ wqkv_bf,
                                            float* __restrict__ bqkv) {
  const int XB = 2304;
  if ((int)blockIdx.x >= XB) {                    // 9 tail blocks: bias concat
    int j = (blockIdx.x - XB) * 256 + threadIdx.x;
    if (j < 768) bqkv[j] = bq[j];
    else if (j < 1536) bqkv[j] = bk[j - 768];
    else if (j < 2304) bqkv[j] = bv[j - 1536];
    return;
  }
  const int n8x = 3145728, n8w = 73728;           // XE/8, WE/8
  const int stride = XB * 256;
  for (int i = blockIdx.x * 256 + threadIdx.x; i < n8x + 3 * n8w; i += stride) {
    const float* s; unsigned short* d;
    if (i < n8x) { s = x + (size_t)i * 8; d = x_bf + (size_t)i * 8; }
    else {
      int wi = i - n8x, w = wi / n8w, off = wi - w * n8w;
      const float* ws_ = (w == 0) ? Wq : (w == 1) ? Wk : Wv;
      s = ws_ + (size_t)off * 8; d = wqkv_bf + (size_t)wi * 8;
    }
    f32x4 a = ((const f32x4*)s)[0], b = ((const f32x4*)s)[1];
    u16x4 lo, hi;
    lo[0] = f2bf(a[0]); lo[1] = f2bf(a[1]); lo[2] = f2bf(a[2]); lo[3] = f2bf(a[3]);
    hi[0] = f2bf(b[0]); hi[1] = f2bf(b[1]); hi[2] = f2bf(b[2]); hi[3] = f2bf(b[3]);
    ((u16x4*)d)[0] = lo; ((u16x4*)d)[1] = hi;
  }
}

// ---------------- gemm256: C[M,N] = A[M,K] @ Bm[N,K]^T + bias ----------------
// BMBLK: BM = 128*BMBLK. BN fixed 256. MODE 0: fp32 out (batched B). MODE 1: QKV epilogue.
template <int MODE, int BMBLK>
__global__ __launch_bounds__(512, 2) void gemm256(const unsigned short* __restrict__ A,
                                                  const unsigned short* __restrict__ Bm,
                                                  const float* __restrict__ bias,
                                                  void* out0, void* out1, void* out2,
                                                  int N, int K, int nb, int batchedB) {
  constexpr int BM = BMBLK * 128;
  __shared__ unsigned short As[2][BM * 64];
  __shared__ unsigned short Bs[2][256 * 64];
  const int tid = threadIdx.x, lane = tid & 63, wid = tid >> 6;
  const int wr = wid >> 2, wc = wid & 3;          // 2 x 4 waves
  const int cpx = gridDim.x >> 3;
  const int logical = (blockIdx.x & 7) * cpx + (blockIdx.x >> 3);
  const int m0 = (logical / nb) * BM, n0 = (logical % nb) * 256;
  const unsigned short* Bp = Bm + (batchedB ? ((size_t)(m0 >> 12) * 589824) : 0);

  f32x4 acc[BMBLK * 4][4] = {};
  const int srcc8 = ((lane & 7) ^ (lane >> 3)) * 8;   // T2: pre-swizzled global col (rule 21)

  auto stageA = [&](int buf, int which, int k0) {     // 2 loads/thread per call
    if constexpr (BMBLK == 2) {
#pragma unroll
      for (int half = 0; half < 2; ++half) {
        int row = half * 128 + which * 64 + (tid >> 3);
        __builtin_amdgcn_global_load_lds(
            (const AS1 void*)(A + (size_t)(m0 + row) * K + k0 + srcc8),
            (AS3 void*)(&As[buf][row * 64 + (tid & 7) * 8]), 16, 0, 0);
      }
    } else {
#pragma unroll
      for (int j = 0; j < 2; ++j) {
        int row = j * 64 + (tid >> 3);
        __builtin_amdgcn_global_load_lds(
            (const AS1 void*)(A + (size_t)(m0 + row) * K + k0 + srcc8),
            (AS3 void*)(&As[buf][row * 64 + (tid & 7) * 8]), 16, 0, 0);
      }
    }
  };
  auto stageB = [&](int buf, int which, int k0) {     // 2 loads/thread per call
#pragma unroll
    for (int j = 0; j < 2; ++j) {
      int idx = tid + j * 512;
      int half = idx >> 9, sub = (idx >> 8) & 1;
      int row = half * 128 + sub * 64 + which * 32 + ((idx & 255) >> 3);
      __builtin_amdgcn_global_load_lds(
          (const AS1 void*)(Bp + (size_t)(n0 + row) * K + k0 + srcc8),
          (AS3 void*)(&Bs[buf][row * 64 + (idx & 7) * 8]), 16, 0, 0);
    }
  };

  const int r15 = lane & 15, hi8 = (lane >> 4) * 8, sw = (lane & 7) * 8;
  s16x8 af[4][2], bf[4][2];
  auto readA = [&](int buf, int grp) {   // 8 x ds_read_b128
    const unsigned short* base = &As[buf][(wr * (BM / 2) + grp * 64) * 64];
#pragma unroll
    for (int i = 0; i < 4; ++i) {
      int lrow = i * 16 + r15;
#pragma unroll
      for (int kk = 0; kk < 2; ++kk)
        af[i][kk] = *(const s16x8*)(base + lrow * 64 + ((kk * 32 + hi8) ^ sw));
    }
  };
  auto readB = [&](int buf, int grp) {   // 4 x ds_read_b128
    const unsigned short* base = &Bs[buf][(wc >> 1) * 128 * 64];
#pragma unroll
    for (int jj = 0; jj < 2; ++jj) {
      int j = grp * 2 + jj;
      int lrow = (wc & 1) * 64 + j * 16 + r15;
#pragma unroll
      for (int kk = 0; kk < 2; ++kk)
        bf[j][kk] = *(const s16x8*)(base + lrow * 64 + ((kk * 32 + hi8) ^ sw));
    }
  };

  // kk OUTER: consecutive MFMAs hit distinct acc regs (dep distance 8)
#define MFMA16(MI0, J0)                                                             \
  __builtin_amdgcn_s_setprio(1);                                                    \
  _Pragma("unroll") for (int kk = 0; kk < 2; ++kk)                                  \
  _Pragma("unroll") for (int i = 0; i < 4; ++i)                                     \
  _Pragma("unroll") for (int jj = 0; jj < 2; ++jj)                                  \
    acc[(MI0) + i][(J0) + jj] = __builtin_amdgcn_mfma_f32_16x16x32_bf16(            \
        af[i][kk], bf[(J0) + jj][kk], acc[(MI0) + i][(J0) + jj], 0, 0, 0);          \
  __builtin_amdgcn_s_setprio(0);

  const int nt = K >> 6;
  // prologue: stage tiles 0,1
  if constexpr (BMBLK == 2) {
    stageA(0, 0, 0);  stageA(0, 1, 0);  stageB(0, 0, 0);  stageB(0, 1, 0);
    stageA(1, 0, 64); stageA(1, 1, 64); stageB(1, 0, 64); stageB(1, 1, 64);
    asm volatile("s_waitcnt vmcnt(8)" ::: "memory");
  } else {
    stageA(0, 0, 0);  stageB(0, 0, 0);  stageB(0, 1, 0);
    stageA(1, 0, 64); stageB(1, 0, 64); stageB(1, 1, 64);
    asm volatile("s_waitcnt vmcnt(6)" ::: "memory");
  }
  __builtin_amdgcn_s_barrier();

  for (int s = 0; s < nt; ++s) {
    const int buf = s & 1;
    const int k2 = (s + 2) << 6;
    const bool pf = (s + 2) < nt;
    if constexpr (BMBLK == 2) {
      // P1: read A_lo + B_lo ; MFMA (mi0-3, j0-1)
      readA(buf, 0); readB(buf, 0);
      asm volatile("" ::: "memory");
      __builtin_amdgcn_s_barrier();
      asm volatile("s_waitcnt lgkmcnt(0)" ::: "memory");
      MFMA16(0, 0)
      asm volatile("" ::: "memory");
      __builtin_amdgcn_s_barrier();
      // P2: read B_hi ; stage A0,B0(s+2) ; MFMA (mi0-3, j2-3)
      readB(buf, 1);
      if (pf) { stageA(buf, 0, k2); stageB(buf, 0, k2); }
      asm volatile("" ::: "memory");
      __builtin_amdgcn_s_barrier();
      asm volatile("s_waitcnt lgkmcnt(0)" ::: "memory");
      MFMA16(0, 2)
      asm volatile("" ::: "memory");
      __builtin_amdgcn_s_barrier();
      // P3: read A_hi ; stage B1(s+2) ; MFMA (mi4-7, j2-3)
      readA(buf, 1);
      if (pf) stageB(buf, 1, k2);
      asm volatile("" ::: "memory");
      __builtin_amdgcn_s_barrier();
      asm volatile("s_waitcnt lgkmcnt(0)" ::: "memory");
      MFMA16(4, 2)
      asm volatile("" ::: "memory");
      __builtin_amdgcn_s_barrier();
      // P4: stage A1(s+2) ; MFMA (mi4-7, j0-1) ; counted gate
      if (pf) stageA(buf, 1, k2);
      MFMA16(4, 0)
      if (pf)              asm volatile("s_waitcnt vmcnt(8)" ::: "memory");
      else if (s + 1 < nt) asm volatile("s_waitcnt vmcnt(0)" ::: "memory");
      __builtin_amdgcn_s_barrier();
    } else {
      // P1: read all A + all B ; MFMA (mi0-3, j0-1)
      readA(buf, 0); readB(buf, 0); readB(buf, 1);
      asm volatile("" ::: "memory");
      __builtin_amdgcn_s_barrier();
      asm volatile("s_waitcnt lgkmcnt(0)" ::: "memory");
      MFMA16(0, 0)
      asm volatile("" ::: "memory");
      __builtin_amdgcn_s_barrier();
      // P2: stage all(s+2) ; MFMA (mi0-3, j2-3) ; counted gate
      if (pf) { stageA(buf, 0, k2); stageB(buf, 0, k2); stageB(buf, 1, k2); }
      MFMA16(0, 2)
      if (pf)              asm volatile("s_waitcnt vmcnt(6)" ::: "memory");
      else if (s + 1 < nt) asm volatile("s_waitcnt vmcnt(0)" ::: "memory");
      __builtin_amdgcn_s_barrier();
    }
  }

  // ---------------- epilogue ----------------
  const int g = lane >> 4, c15 = lane & 15;
  float bj[4];
#pragma unroll
  for (int j = 0; j < 4; ++j) bj[j] = bias[n0 + wc * 64 + j * 16 + c15];

  if (MODE == 0) {
    float* out = (float*)out0;
#pragma unroll
    for (int mi = 0; mi < BMBLK * 4; ++mi)
#pragma unroll
      for (int j = 0; j < 4; ++j) {
        int gr = m0 + wr * (BM / 2) + mi * 16 + g * 4;
        int gc = n0 + wc * 64 + j * 16 + c15;
#pragma unroll
        for (int r = 0; r < 4; ++r)
          out[(size_t)(gr + r) * N + gc] = acc[mi][j][r] + bj[j];
      }
  } else {
    if (n0 < 768) {            // q block: per-row softmax over this wave's 64 cols (one head)
      unsigned short* qsm = (unsigned short*)out0;
      const int cbase = n0 + wc * 64;
#pragma unroll
      for (int mi = 0; mi < BMBLK * 4; ++mi) {
#pragma unroll
        for (int r = 0; r < 4; ++r) {
          int gr = m0 + wr * (BM / 2) + mi * 16 + g * 4 + r;
          float v[4];
#pragma unroll
          for (int j = 0; j < 4; ++j) v[j] = acc[mi][j][r] + bj[j];
          float mx = fmaxf(fmaxf(v[0], v[1]), fmaxf(v[2], v[3]));
#pragma unroll
          for (int st = 1; st < 16; st <<= 1) mx = fmaxf(mx, __shfl_xor(mx, st));
          float p[4], sm = 0.f;
#pragma unroll
          for (int j = 0; j < 4; ++j) { p[j] = __expf(v[j] - mx); sm += p[j]; }
#pragma unroll
          for (int st = 1; st < 16; st <<= 1) sm += __shfl_xor(sm, st);
          float inv = 1.0f / sm;
#pragma unroll
          for (int j = 0; j < 4; ++j)
            qsm[(size_t)gr * 768 + cbase + j * 16 + c15] = f2bf(p[j] * inv);
        }
      }
    } else {                   // k or v block: fp16 compact store
      _Float16* dst = (n0 < 1536) ? (_Float16*)out1 : (_Float16*)out2;
      const int cbase = (n0 < 1536 ? n0 - 768 : n0 - 1536) + wc * 64;
#pragma unroll
      for (int mi = 0; mi < BMBLK * 4; ++mi)
#pragma unroll
        for (int j = 0; j < 4; ++j) {
          int gr = m0 + wr * (BM / 2) + mi * 16 + g * 4;
          int cc = cbase + j * 16 + c15;
#pragma unroll
          for (int r = 0; r < 4; ++r)
            dst[(size_t)(gr + r) * 768 + cc] = (_Float16)(acc[mi][j][r] + bj[j]);
        }
    }
  }
#undef MFMA16
}

// ---------------- KV partial: kv_raw[bh,d,e] += sum_n exp(k[n,d]) v[n,e]; z += sum exp(k) ----------------
__global__ __launch_bounds__(256) void kv_partial(const _Float16* __restrict__ kh,
                                                  const _Float16* __restrict__ vh,
                                                  float* __restrict__ kv_raw,
                                                  float* __restrict__ z_raw) {
  const int bh = blockIdx.x, b = bh / 12, h = bh % 12;
  const int split = blockIdx.y;
  __shared__ float ek_s[64][68];
  __shared__ float v_s[64][68];
  const int t = threadIdx.x;
  const int d0 = (t >> 4) * 4, e0 = (t & 15) * 4;
  const int zd = t & 63, zq = t >> 6;
  float acc[4][4] = {};
  float zp = 0.f;
  const size_t base = (size_t)b * 4096 * 768 + h * 64;

  for (int nc = 0; nc < 8; ++nc) {
    int n0 = split * 512 + nc * 64;
#pragma unroll
    for (int j = 0; j < 2; ++j) {                  // 512 x 16B ops cover 64x64
      int vi = t + j * 256;
      int row = vi >> 3, c8 = (vi & 7) * 8;
      size_t gp = base + (size_t)(n0 + row) * 768 + c8;
      f16x8 k8 = *(const f16x8*)(kh + gp);
      f16x8 v8 = *(const f16x8*)(vh + gp);
      f32x4 e0v, e1v, v0v, v1v;
#pragma unroll
      for (int u = 0; u < 4; ++u) {
        e0v[u] = __expf((float)k8[u]); e1v[u] = __expf((float)k8[4 + u]);
        v0v[u] = (float)v8[u];         v1v[u] = (float)v8[4 + u];
      }
      *(f32x4*)&ek_s[row][c8] = e0v; *(f32x4*)&ek_s[row][c8 + 4] = e1v;
      *(f32x4*)&v_s[row][c8]  = v0v; *(f32x4*)&v_s[row][c8 + 4]  = v1v;
    }
    __syncthreads();
#pragma unroll 4
    for (int r = 0; r < 16; ++r) zp += ek_s[zq * 16 + r][zd];
#pragma unroll 8
    for (int n = 0; n < 64; ++n) {
      f32x4 ekv = *(const f32x4*)&ek_s[n][d0];
      f32x4 vv  = *(const f32x4*)&v_s[n][e0];
#pragma unroll
      for (int i = 0; i < 4; ++i)
#pragma unroll
        for (int j = 0; j < 4; ++j)
          acc[i][j] += ekv[i] * vv[j];
    }
    __syncthreads();
  }
  float* kvp = kv_raw + (size_t)bh * 4096;
#pragma unroll
  for (int i = 0; i < 4; ++i)
#pragma unroll
    for (int j = 0; j < 4; ++j)
      atomicAdd(&kvp[(d0 + i) * 64 + e0 + j], acc[i][j]);
  atomicAdd(&z_raw[bh * 64 + zd], zp);
}

// ---------------- Weff: weffT[b][c][h*64+d] = sum_e kv_n[b,h,d,e] * Wp[c][h*64+e] ----------------
__global__ __launch_bounds__(256) void weff_build(const float* __restrict__ kv_raw,
                                                  const float* __restrict__ z_raw,
                                                  const float* __restrict__ Wp,
                                                  unsigned short* __restrict__ weffT) {
  const int c0 = blockIdx.x * 64, h = blockIdx.y, b = blockIdx.z;
  const int bh = b * 12 + h;
  __shared__ float kvn[64][65];
  const int t = threadIdx.x;
#pragma unroll
  for (int i = 0; i < 16; ++i) {
    int idx = t + i * 256;
    int d = idx >> 6;
    kvn[d][idx & 63] = kv_raw[(size_t)bh * 4096 + idx] / (z_raw[bh * 64 + d] * 8.0f);
  }
  __syncthreads();
  const int c = c0 + (t >> 2);
  const int d0 = (t & 3) * 16;
  const float* wrow = Wp + (size_t)c * 768 + h * 64;
  float acc[16] = {};
#pragma unroll 8
  for (int e = 0; e < 64; ++e) {
    float w = wrow[e];
#pragma unroll
    for (int dd = 0; dd < 16; ++dd) acc[dd] += w * kvn[d0 + dd][e];
  }
  unsigned short* orow = weffT + (size_t)b * 589824 + (size_t)c * 768 + h * 64 + d0;
#pragma unroll
  for (int dd = 0; dd < 16; ++dd) orow[dd] = f2bf(acc[dd]);
}

// ---------------- launch ----------------
extern "C" void kernel_launch(void* const* d_in, const int* in_sizes, int n_in,
                              void* d_out, int out_size, void* d_ws, size_t ws_size,
                              hipStream_t stream) {
  const float* x  = (const float*)d_in[0];
  const float* Wq = (const float*)d_in[1];
  const float* bq = (const float*)d_in[2];
  const float* Wk = (const float*)d_in[3];
  const float* bk = (const float*)d_in[4];
  const float* Wv = (const float*)d_in[5];
  const float* bv = (const float*)d_in[6];
  const float* Wp = (const float*)d_in[7];
  const float* bp = (const float*)d_in[8];

  const size_t MT = 32768;
  const size_t XE = MT * 768;
  const size_t WE = 768 * 768;

  unsigned short* x_bf    = (unsigned short*)d_ws;           // 48 MB
  unsigned short* wqkv_bf = x_bf + XE;                        // 3.4 MB
  unsigned short* q_sm    = wqkv_bf + 3 * WE;                 // 48 MB (bf16 softmaxed q)
  _Float16* k_h = (_Float16*)(q_sm + XE);                     // 48 MB
  _Float16* v_h = k_h + XE;                                   // 48 MB
  unsigned short* weffT = (unsigned short*)(v_h + XE);        // 9.4 MB
  float* bqkv   = (float*)(weffT + 8 * WE);
  float* kv_raw = bqkv + 2304;
  float* z_raw  = kv_raw + 96 * 4096;

  prep<<<2313, 256, 0, stream>>>(x, Wq, Wk, Wv, bq, bk, bv, x_bf, wqkv_bf, bqkv);
  hipMemsetAsync(kv_raw, 0, (96 * 4096 + 96 * 64) * sizeof(float), stream);

  // fused QKV GEMM: [32768,768] x [2304,768]^T ; epilogue q-softmax / k,v fp16
  gemm256<1, 2><<<1152, 512, 0, stream>>>(x_bf, wqkv_bf, bqkv, q_sm, k_h, v_h, 2304, 768, 9, 0);

  kv_partial<<<dim3(96, 8), 256, 0, stream>>>(k_h, v_h, kv_raw, z_raw);
  weff_build<<<dim3(12, 12, 8), 256, 0, stream>>>(kv_raw, z_raw, Wp, weffT);

  // out = q_sm @ Weff_b^T + bp  (BM=128: 768 blocks = 3 clean rounds)
  gemm256<0, 1><<<768, 512, 0, stream>>>(q_sm, weffT, bp, d_out, nullptr, nullptr, 768, 768, 3, 1);
}